// Round 1
// baseline (136.489 us; speedup 1.0000x reference)
//
#include <hip/hip_runtime.h>
#include <hip/hip_bf16.h>
#include <stdint.h>

#define N_NODES 2048
#define FDIM 256

typedef short bf16x8 __attribute__((ext_vector_type(8)));   // 8 bf16 = 4 VGPRs (MFMA A/B frag)
typedef float f32x4 __attribute__((ext_vector_type(4)));

// ---------------- k_pack: adj int32 -> bitmask (adjp[i][w], bit j&31 of word j>>5) -------------
__global__ __launch_bounds__(256) void k_pack(const int* __restrict__ adj, uint32_t* __restrict__ adjp) {
  int t = threadIdx.x;
  int lane = t & 63;
  int i = blockIdx.x * 4 + (t >> 6);
  const int* row = adj + (size_t)i * N_NODES;
  #pragma unroll
  for (int it = 0; it < 32; ++it) {
    int v = row[it * 64 + lane];
    unsigned long long m = __ballot(v != 0);
    if (lane == 0) {
      adjp[i * 64 + it * 2]     = (uint32_t)(m & 0xffffffffull);
      adjp[i * 64 + it * 2 + 1] = (uint32_t)(m >> 32);
    }
  }
}

// ---------------- k_h: h = inp@W (fp32), e_src=h.a1, e_dst=h.a2, hT = bf16 transpose ----------
// block: 256 thr, 32 rows x 256 cols, K=256. A tile in LDS, W streamed (L2-hot, 256KB).
__global__ __launch_bounds__(256) void k_h(const float* __restrict__ inp, const float* __restrict__ W,
                                           const float* __restrict__ a,
                                           __hip_bfloat16* __restrict__ hT,
                                           float* __restrict__ e_src, float* __restrict__ e_dst) {
  __shared__ float smem[32 * 260];   // 33.3 KB; later reused as bf16 transpose buffer [256][40]
  int t = threadIdx.x;
  int r0 = blockIdx.x * 32;          // flat row (b*2048 + j), block stays within one batch
  int b = r0 >> 11;
  int j0 = r0 & (N_NODES - 1);

  {                                   // stage A tile [32][256] (+pad 4 per row)
    int r = t >> 3, c0 = (t & 7) * 4;
    #pragma unroll
    for (int it = 0; it < 8; ++it) {
      int c = c0 + it * 32;
      *(f32x4*)(&smem[r * 260 + c]) = *(const f32x4*)(inp + (size_t)(r0 + r) * FDIM + c);
    }
  }
  __syncthreads();

  int ry = t >> 5;   // 0..7 -> rows ry*4..+4
  int cx = t & 31;   // 0..31 -> cols cx*8..+8
  float acc[4][8];
  #pragma unroll
  for (int i = 0; i < 4; ++i)
    #pragma unroll
    for (int j = 0; j < 8; ++j) acc[i][j] = 0.f;

  #pragma unroll 2
  for (int k0 = 0; k0 < 256; k0 += 4) {
    f32x4 ar[4];
    #pragma unroll
    for (int rr = 0; rr < 4; ++rr) ar[rr] = *(const f32x4*)(&smem[(ry * 4 + rr) * 260 + k0]);
    #pragma unroll
    for (int kk = 0; kk < 4; ++kk) {
      f32x4 w0 = *(const f32x4*)(W + (size_t)(k0 + kk) * FDIM + cx * 8);
      f32x4 w1 = *(const f32x4*)(W + (size_t)(k0 + kk) * FDIM + cx * 8 + 4);
      #pragma unroll
      for (int rr = 0; rr < 4; ++rr) {
        float av = ar[rr][kk];
        #pragma unroll
        for (int cc = 0; cc < 4; ++cc) acc[rr][cc]     = fmaf(av, w0[cc], acc[rr][cc]);
        #pragma unroll
        for (int cc = 0; cc < 4; ++cc) acc[rr][cc + 4] = fmaf(av, w1[cc], acc[rr][cc + 4]);
      }
    }
  }

  // fused e_src/e_dst: per-row dot with a1/a2, reduce across the 32-lane col group
  f32x4 a10 = *(const f32x4*)(a + cx * 8);
  f32x4 a11 = *(const f32x4*)(a + cx * 8 + 4);
  f32x4 a20 = *(const f32x4*)(a + 256 + cx * 8);
  f32x4 a21 = *(const f32x4*)(a + 256 + cx * 8 + 4);
  #pragma unroll
  for (int rr = 0; rr < 4; ++rr) {
    float s1 = 0.f, s2 = 0.f;
    #pragma unroll
    for (int cc = 0; cc < 4; ++cc) {
      s1 += acc[rr][cc] * a10[cc] + acc[rr][cc + 4] * a11[cc];
      s2 += acc[rr][cc] * a20[cc] + acc[rr][cc + 4] * a21[cc];
    }
    #pragma unroll
    for (int m = 1; m <= 16; m <<= 1) {
      s1 += __shfl_xor(s1, m);
      s2 += __shfl_xor(s2, m);
    }
    if (cx == 0) {
      int row = r0 + ry * 4 + rr;
      e_src[row] = s1;
      e_dst[row] = s2;
    }
  }

  // transpose to bf16 hT[b][f][j] via LDS (reuse smem)
  __syncthreads();
  __hip_bfloat16* Tsm = (__hip_bfloat16*)smem;  // [256][40] padded
  #pragma unroll
  for (int rr = 0; rr < 4; ++rr)
    #pragma unroll
    for (int cc = 0; cc < 8; ++cc)
      Tsm[(cx * 8 + cc) * 40 + ry * 4 + rr] = __float2bfloat16(acc[rr][cc]);
  __syncthreads();
  {
    int c = t;
    size_t base = ((size_t)b * FDIM + c) * N_NODES + j0;
    #pragma unroll
    for (int q = 0; q < 4; ++q) {
      uint4 v = *(const uint4*)(Tsm + c * 40 + q * 8);
      *(uint4*)(hT + base + q * 8) = v;
    }
  }
}

// ---------------- k_ml: per (b,i) row: m = max_j masked-e, il = 1/sum exp(e-m) -----------------
__global__ __launch_bounds__(256) void k_ml(const uint32_t* __restrict__ adjp,
                                            const float* __restrict__ e_src,
                                            const float* __restrict__ e_dst,
                                            float* __restrict__ mrow, float* __restrict__ ilrow) {
  int t = threadIdx.x;
  int lane = t & 63;
  int r = blockIdx.x * 4 + (t >> 6);      // flat row 0..16383
  int b = r >> 11, i = r & (N_NODES - 1);
  float es = e_src[r];
  const float* edb = e_dst + ((size_t)b << 11);
  const uint32_t* arow = adjp + (size_t)i * 64;
  float ev[32];
  float mx = -3e38f;
  #pragma unroll
  for (int it = 0; it < 32; ++it) {
    int j = it * 64 + lane;
    float ed = edb[j];
    uint32_t w = arow[j >> 5];
    float s = es + ed;
    float lr = fmaxf(s, 0.01f * s);
    float e = ((w >> (j & 31)) & 1u) ? lr : -1e9f;   // exact reference sentinel
    ev[it] = e;
    mx = fmaxf(mx, e);
  }
  #pragma unroll
  for (int m = 1; m <= 32; m <<= 1) mx = fmaxf(mx, __shfl_xor(mx, m));
  float sum = 0.f;
  #pragma unroll
  for (int it = 0; it < 32; ++it) sum += __expf(ev[it] - mx);
  #pragma unroll
  for (int m = 1; m <= 32; m <<= 1) sum += __shfl_xor(sum, m);
  if (lane == 0) { mrow[r] = mx; ilrow[r] = 1.0f / sum; }
}

// ---------------- k_pv: out = relu(P @ H) with P computed on the fly, bf16 MFMA ----------------
// block: 256 thr (4 waves), 32 i-rows x 256 f-cols, K-loop over j in steps of 32.
__global__ __launch_bounds__(256) void k_pv(const __hip_bfloat16* __restrict__ hT,
                                            const uint32_t* __restrict__ adjp,
                                            const float* __restrict__ e_src,
                                            const float* __restrict__ e_dst,
                                            const float* __restrict__ mrow,
                                            const float* __restrict__ ilrow,
                                            float* __restrict__ out) {
  __shared__ __hip_bfloat16 Psm[32 * 40];    // P tile  [32 i][32 j] pad->40 (80B rows)
  __shared__ __hip_bfloat16 Bsm[256 * 40];   // H^T tile [256 f][32 j] pad->40
  int t = threadIdx.x;
  int bb = blockIdx.x >> 6;
  int i0 = (blockIdx.x & 63) * 32;
  int ip = t >> 3, jq = t & 7;               // P compute: thread -> row ip, j quad jq*4
  int rflat = (bb << 11) + i0 + ip;
  float es = e_src[rflat], mi = mrow[rflat], ili = ilrow[rflat];
  const uint32_t* arow = adjp + (size_t)(i0 + ip) * 64;
  const float* edb = e_dst + ((size_t)bb << 11);
  const __hip_bfloat16* hTb = hT + (size_t)bb * FDIM * N_NODES;
  int lane = t & 63, wv = t >> 6, l15 = lane & 15, lq = lane >> 4;

  f32x4 acc[2][4];
  #pragma unroll
  for (int mf = 0; mf < 2; ++mf)
    #pragma unroll
    for (int nf = 0; nf < 4; ++nf)
      #pragma unroll
      for (int e = 0; e < 4; ++e) acc[mf][nf][e] = 0.f;

  for (int js = 0; js < N_NODES; js += 32) {
    // --- compute 4 P values -> bf16 -> LDS
    uint32_t word = arow[js >> 5];
    f32x4 ed = *(const f32x4*)(edb + js + jq * 4);
    unsigned short ub[4];
    #pragma unroll
    for (int d = 0; d < 4; ++d) {
      float s = es + ed[d];
      float lr = fmaxf(s, 0.01f * s);
      float e = ((word >> (jq * 4 + d)) & 1u) ? lr : -1e9f;
      float p = __expf(e - mi) * ili;
      __hip_bfloat16 hb = __float2bfloat16(p);
      ub[d] = __builtin_bit_cast(unsigned short, hb);
    }
    uint2 pk;
    pk.x = (uint32_t)ub[0] | ((uint32_t)ub[1] << 16);
    pk.y = (uint32_t)ub[2] | ((uint32_t)ub[3] << 16);
    *(uint2*)((char*)Psm + ip * 80 + jq * 8) = pk;
    // --- stage H^T tile: 256 rows x 64B
    #pragma unroll
    for (int pp = 0; pp < 4; ++pp) {
      int f = (t >> 2) + pp * 64;
      int pt = t & 3;
      uint4 v = *(const uint4*)(hTb + (size_t)f * N_NODES + js + pt * 8);
      *(uint4*)((char*)Bsm + f * 80 + pt * 16) = v;
    }
    __syncthreads();
    // --- fragments + 8 MFMAs per wave
    bf16x8 afrag[2], bfrag[4];
    #pragma unroll
    for (int mf = 0; mf < 2; ++mf)
      afrag[mf] = *(const bf16x8*)((const char*)Psm + (mf * 16 + l15) * 80 + lq * 16);
    #pragma unroll
    for (int nf = 0; nf < 4; ++nf)
      bfrag[nf] = *(const bf16x8*)((const char*)Bsm + (wv * 64 + nf * 16 + l15) * 80 + lq * 16);
    #pragma unroll
    for (int mf = 0; mf < 2; ++mf)
      #pragma unroll
      for (int nf = 0; nf < 4; ++nf)
        acc[mf][nf] = __builtin_amdgcn_mfma_f32_16x16x32_bf16(afrag[mf], bfrag[nf], acc[mf][nf], 0, 0, 0);
    __syncthreads();
  }

  // epilogue: relu + store (C layout: col = lane&15, row = (lane>>4)*4 + r)
  #pragma unroll
  for (int mf = 0; mf < 2; ++mf)
    #pragma unroll
    for (int nf = 0; nf < 4; ++nf)
      #pragma unroll
      for (int r = 0; r < 4; ++r) {
        int row = i0 + mf * 16 + lq * 4 + r;
        int col = wv * 64 + nf * 16 + l15;
        out[((size_t)bb * N_NODES + row) * FDIM + col] = fmaxf(acc[mf][nf][r], 0.0f);
      }
}

extern "C" void kernel_launch(void* const* d_in, const int* in_sizes, int n_in,
                              void* d_out, int out_size, void* d_ws, size_t ws_size,
                              hipStream_t stream) {
  const float* inp = (const float*)d_in[0];
  const int*   adj = (const int*)d_in[1];
  const float* W   = (const float*)d_in[2];
  const float* a   = (const float*)d_in[3];
  float* out = (float*)d_out;

  char* ws = (char*)d_ws;
  __hip_bfloat16* hT = (__hip_bfloat16*)ws;             // 8 * 256 * 2048 * 2B = 8,388,608
  uint32_t* adjp = (uint32_t*)(ws + 8388608);           // 2048 * 64 * 4B     =   524,288
  float* e_src = (float*)(ws + 8912896);                // 16384 * 4
  float* e_dst = (float*)(ws + 8978432);
  float* mrow  = (float*)(ws + 9043968);
  float* ilrow = (float*)(ws + 9109504);                // end ~9.18 MB

  k_pack<<<512, 256, 0, stream>>>(adj, adjp);
  k_h<<<512, 256, 0, stream>>>(inp, W, a, hT, e_src, e_dst);
  k_ml<<<4096, 256, 0, stream>>>(adjp, e_src, e_dst, mrow, ilrow);
  k_pv<<<512, 256, 0, stream>>>(hT, adjp, e_src, e_dst, mrow, ilrow, out);
}

// Round 2
// 126.758 us; speedup vs baseline: 1.0768x; 1.0768x over previous
//
#include <hip/hip_runtime.h>
#include <hip/hip_bf16.h>
#include <stdint.h>

#define N_NODES 2048
#define FDIM 256

typedef short bf16x8 __attribute__((ext_vector_type(8)));   // 8 bf16 = 4 VGPRs (MFMA A/B frag)
typedef float f32x4 __attribute__((ext_vector_type(4)));
typedef unsigned short u16x4 __attribute__((ext_vector_type(4)));

static __device__ __forceinline__ unsigned short bf16r(float x) {
  __hip_bfloat16 h = __float2bfloat16(x);
  return __builtin_bit_cast(unsigned short, h);
}

// ---------------- k_pack: adj int32 -> bitmask ------------------------------------------------
__global__ __launch_bounds__(256) void k_pack(const int* __restrict__ adj, uint32_t* __restrict__ adjp) {
  int t = threadIdx.x;
  int lane = t & 63;
  int i = blockIdx.x * 4 + (t >> 6);
  const int* row = adj + (size_t)i * N_NODES;
  #pragma unroll
  for (int it = 0; it < 32; ++it) {
    int v = row[it * 64 + lane];
    unsigned long long m = __ballot(v != 0);
    if (lane == 0) {
      adjp[i * 64 + it * 2]     = (uint32_t)(m & 0xffffffffull);
      adjp[i * 64 + it * 2 + 1] = (uint32_t)(m >> 32);
    }
  }
}

// ---------------- k_prep: WT16 = bf16(W^T) [f][k]; wa1 = W@a1, wa2 = W@a2 (fp32) ---------------
__global__ __launch_bounds__(256) void k_prep(const float* __restrict__ W, const float* __restrict__ a,
                                              __hip_bfloat16* __restrict__ WT16,
                                              float* __restrict__ wa1, float* __restrict__ wa2) {
  int bid = blockIdx.x, t = threadIdx.x;
  if (bid < 16) {
    __shared__ __hip_bfloat16 T[64][67];
    int k0 = (bid & 3) * 64, f0 = (bid >> 2) * 64;
    int r = t >> 2, c0 = (t & 3) * 16;
    #pragma unroll
    for (int i = 0; i < 4; ++i) {
      f32x4 v = *(const f32x4*)(W + (size_t)(k0 + r) * FDIM + f0 + c0 + i * 4);
      #pragma unroll
      for (int j = 0; j < 4; ++j) T[r][c0 + i * 4 + j] = __float2bfloat16(v[j]);
    }
    __syncthreads();
    int fr = t >> 2, kc = (t & 3) * 16;
    unsigned short buf[16];
    #pragma unroll
    for (int i = 0; i < 16; ++i) buf[i] = __builtin_bit_cast(unsigned short, T[kc + i][fr]);
    uint4* dst = (uint4*)(WT16 + (size_t)(f0 + fr) * FDIM + k0 + kc);
    dst[0] = *(uint4*)&buf[0];
    dst[1] = *(uint4*)&buf[8];
  } else {
    int k = (bid - 16) * 64 + (t >> 2), q = t & 3;
    float s1 = 0.f, s2 = 0.f;
    #pragma unroll
    for (int i = 0; i < 16; ++i) {
      int f = q * 64 + i * 4;
      f32x4 w  = *(const f32x4*)(W + (size_t)k * FDIM + f);
      f32x4 v1 = *(const f32x4*)(a + f);
      f32x4 v2 = *(const f32x4*)(a + FDIM + f);
      #pragma unroll
      for (int j = 0; j < 4; ++j) { s1 += w[j] * v1[j]; s2 += w[j] * v2[j]; }
    }
    s1 += __shfl_xor(s1, 1); s1 += __shfl_xor(s1, 2);
    s2 += __shfl_xor(s2, 1); s2 += __shfl_xor(s2, 2);
    if (q == 0) { wa1[k] = s1; wa2[k] = s2; }
  }
}

// ---------------- k_h: hT = bf16(inp@W)^T via MFMA; e_src/e_dst = inp@wa (exact fp32) ----------
// block: 256 thr (4 waves), tile 32 j-rows x 256 f. A staged bf16 in LDS, B from WT16 (L2-hot).
__global__ __launch_bounds__(256) void k_h(const float* __restrict__ inp,
                                           const __hip_bfloat16* __restrict__ WT16,
                                           const float* __restrict__ wa1, const float* __restrict__ wa2,
                                           __hip_bfloat16* __restrict__ hT,
                                           float* __restrict__ e_src, float* __restrict__ e_dst) {
  __shared__ char lds_raw[20480];
  __hip_bfloat16* Asm = (__hip_bfloat16*)lds_raw;  // [32][264] bf16
  int t = threadIdx.x;
  int r0 = blockIdx.x * 32;
  int b = r0 >> 11, j0 = r0 & (N_NODES - 1);
  {
    int r = t >> 3, q = t & 7, c0 = q * 32;
    const float* ip = inp + (size_t)(r0 + r) * FDIM + c0;
    float s1 = 0.f, s2 = 0.f;
    #pragma unroll
    for (int i = 0; i < 8; ++i) {
      f32x4 v  = *(const f32x4*)(ip + i * 4);
      f32x4 u1 = *(const f32x4*)(wa1 + c0 + i * 4);
      f32x4 u2 = *(const f32x4*)(wa2 + c0 + i * 4);
      u16x4 pk;
      #pragma unroll
      for (int j = 0; j < 4; ++j) {
        s1 += v[j] * u1[j];
        s2 += v[j] * u2[j];
        pk[j] = bf16r(v[j]);
      }
      *(u16x4*)(Asm + r * 264 + c0 + i * 4) = pk;
    }
    s1 += __shfl_xor(s1, 1); s1 += __shfl_xor(s1, 2); s1 += __shfl_xor(s1, 4);
    s2 += __shfl_xor(s2, 1); s2 += __shfl_xor(s2, 2); s2 += __shfl_xor(s2, 4);
    if (q == 0) { e_src[r0 + r] = s1; e_dst[r0 + r] = s2; }
  }
  __syncthreads();

  int lane = t & 63, wv = t >> 6, l15 = lane & 15, lq = lane >> 4;
  int f0 = wv * 64;
  f32x4 acc[2][4];
  #pragma unroll
  for (int mf = 0; mf < 2; ++mf)
    #pragma unroll
    for (int nf = 0; nf < 4; ++nf)
      #pragma unroll
      for (int e = 0; e < 4; ++e) acc[mf][nf][e] = 0.f;

  #pragma unroll
  for (int ks = 0; ks < 8; ++ks) {
    int k0 = ks * 32;
    bf16x8 af[2], bfr[4];
    #pragma unroll
    for (int mf = 0; mf < 2; ++mf)
      af[mf] = *(const bf16x8*)(Asm + (mf * 16 + l15) * 264 + k0 + lq * 8);
    #pragma unroll
    for (int nf = 0; nf < 4; ++nf)
      bfr[nf] = *(const bf16x8*)(WT16 + (size_t)(f0 + nf * 16 + l15) * FDIM + k0 + lq * 8);
    #pragma unroll
    for (int mf = 0; mf < 2; ++mf)
      #pragma unroll
      for (int nf = 0; nf < 4; ++nf)
        acc[mf][nf] = __builtin_amdgcn_mfma_f32_16x16x32_bf16(af[mf], bfr[nf], acc[mf][nf], 0, 0, 0);
  }

  __syncthreads();
  __hip_bfloat16* Tsm = (__hip_bfloat16*)lds_raw;  // [256][40] bf16
  #pragma unroll
  for (int mf = 0; mf < 2; ++mf)
    #pragma unroll
    for (int nf = 0; nf < 4; ++nf) {
      u16x4 pk;
      #pragma unroll
      for (int r = 0; r < 4; ++r) pk[r] = bf16r(acc[mf][nf][r]);
      int fl = f0 + nf * 16 + l15;
      int jl = mf * 16 + lq * 4;
      *(u16x4*)(Tsm + fl * 40 + jl) = pk;
    }
  __syncthreads();
  {
    const uint4* src = (const uint4*)(Tsm + t * 40);
    uint4* dst = (uint4*)(hT + ((size_t)b * FDIM + t) * N_NODES + j0);
    dst[0] = src[0]; dst[1] = src[1]; dst[2] = src[2]; dst[3] = src[3];
  }
}

// ---------------- k_ml: per (b,i) row: m = max_j masked-e, il = 1/sum exp(e-m) -----------------
__global__ __launch_bounds__(256) void k_ml(const uint32_t* __restrict__ adjp,
                                            const float* __restrict__ e_src,
                                            const float* __restrict__ e_dst,
                                            float* __restrict__ mrow, float* __restrict__ ilrow) {
  int t = threadIdx.x;
  int lane = t & 63;
  int r = blockIdx.x * 4 + (t >> 6);
  int b = r >> 11, i = r & (N_NODES - 1);
  float es = e_src[r];
  const float* edb = e_dst + ((size_t)b << 11);
  const uint32_t* arow = adjp + (size_t)i * 64;
  float ev[32];
  float mx = -3e38f;
  #pragma unroll
  for (int it = 0; it < 32; ++it) {
    int j = it * 64 + lane;
    float ed = edb[j];
    uint32_t w = arow[j >> 5];
    float s = es + ed;
    float lr = fmaxf(s, 0.01f * s);
    float e = ((w >> (j & 31)) & 1u) ? lr : -1e9f;
    ev[it] = e;
    mx = fmaxf(mx, e);
  }
  #pragma unroll
  for (int m = 1; m <= 32; m <<= 1) mx = fmaxf(mx, __shfl_xor(mx, m));
  float sum = 0.f;
  #pragma unroll
  for (int it = 0; it < 32; ++it) sum += __expf(ev[it] - mx);
  #pragma unroll
  for (int m = 1; m <= 32; m <<= 1) sum += __shfl_xor(sum, m);
  if (lane == 0) { mrow[r] = mx; ilrow[r] = 1.0f / sum; }
}

// ---------------- k_pv: out = relu(P @ H); P on the fly (dbuf LDS), B direct from L2 -----------
// tile 64 i x 128 f, 256 thr (4 waves: wm=wv>>1, wn=wv&1; wave = 32i x 64f, 8 MFMA/step).
// grid 512: bid&7 = batch (XCD-pinned), (bid>>3)&31 = i-tile, bid>>8 = f-half.
__global__ __launch_bounds__(256) void k_pv(const __hip_bfloat16* __restrict__ hT,
                                            const uint32_t* __restrict__ adjp,
                                            const float* __restrict__ e_src,
                                            const float* __restrict__ e_dst,
                                            const float* __restrict__ mrow,
                                            const float* __restrict__ ilrow,
                                            float* __restrict__ out) {
  __shared__ __hip_bfloat16 Psm[2][64 * 40];   // P tile [64 i][32 j] pad->40 (80B rows), dbuf
  int t = threadIdx.x;
  int bb = blockIdx.x & 7;
  int i0 = ((blockIdx.x >> 3) & 31) * 64;
  int fh = (blockIdx.x >> 8) * 128;
  int ip = t >> 2, jq = t & 3;                 // P compute: row ip, 8 j's at jq*8
  int rflat = (bb << 11) + i0 + ip;
  float es = e_src[rflat], mi = mrow[rflat], ili = ilrow[rflat];
  const uint32_t* arow = adjp + (size_t)(i0 + ip) * 64;
  const float* edb = e_dst + ((size_t)bb << 11);
  const __hip_bfloat16* hTb = hT + (size_t)bb * FDIM * N_NODES;
  int lane = t & 63, wv = t >> 6, l15 = lane & 15, lq = lane >> 4;
  int wm = wv >> 1, wn = wv & 1;
  const __hip_bfloat16* bp[4];
  #pragma unroll
  for (int nf = 0; nf < 4; ++nf)
    bp[nf] = hTb + (size_t)(fh + wn * 64 + nf * 16 + l15) * N_NODES + lq * 8;

  auto computeP = [&](int js) -> uint4 {
    uint32_t word = arow[js >> 5] >> (jq * 8);
    f32x4 e0 = *(const f32x4*)(edb + js + jq * 8);
    f32x4 e1 = *(const f32x4*)(edb + js + jq * 8 + 4);
    unsigned short u[8];
    #pragma unroll
    for (int d = 0; d < 8; ++d) {
      float edv = (d < 4) ? e0[d] : e1[d & 3];
      float s = es + edv;
      float lr = fmaxf(s, 0.01f * s);
      float e = ((word >> d) & 1u) ? lr : -1e9f;
      u[d] = bf16r(__expf(e - mi) * ili);
    }
    uint4 r;
    r.x = (uint32_t)u[0] | ((uint32_t)u[1] << 16);
    r.y = (uint32_t)u[2] | ((uint32_t)u[3] << 16);
    r.z = (uint32_t)u[4] | ((uint32_t)u[5] << 16);
    r.w = (uint32_t)u[6] | ((uint32_t)u[7] << 16);
    return r;
  };

  f32x4 acc[2][4];
  #pragma unroll
  for (int mf = 0; mf < 2; ++mf)
    #pragma unroll
    for (int nf = 0; nf < 4; ++nf)
      #pragma unroll
      for (int e = 0; e < 4; ++e) acc[mf][nf][e] = 0.f;

  {
    uint4 p0 = computeP(0);
    *(uint4*)((char*)Psm[0] + ip * 80 + jq * 16) = p0;
  }
  bf16x8 bcur[4];
  #pragma unroll
  for (int nf = 0; nf < 4; ++nf) bcur[nf] = *(const bf16x8*)(bp[nf]);
  __syncthreads();

  int cur = 0;
  for (int js = 0; js < N_NODES; js += 32) {
    bf16x8 bn[4];
    bool more = (js + 32) < N_NODES;
    if (more) {
      #pragma unroll
      for (int nf = 0; nf < 4; ++nf) bn[nf] = *(const bf16x8*)(bp[nf] + js + 32);
      uint4 pn = computeP(js + 32);
      *(uint4*)((char*)Psm[cur ^ 1] + ip * 80 + jq * 16) = pn;
    }
    bf16x8 af[2];
    #pragma unroll
    for (int mf = 0; mf < 2; ++mf)
      af[mf] = *(const bf16x8*)((char*)Psm[cur] + (wm * 32 + mf * 16 + l15) * 80 + lq * 16);
    #pragma unroll
    for (int mf = 0; mf < 2; ++mf)
      #pragma unroll
      for (int nf = 0; nf < 4; ++nf)
        acc[mf][nf] = __builtin_amdgcn_mfma_f32_16x16x32_bf16(af[mf], bcur[nf], acc[mf][nf], 0, 0, 0);
    __syncthreads();
    if (more) {
      #pragma unroll
      for (int nf = 0; nf < 4; ++nf) bcur[nf] = bn[nf];
    }
    cur ^= 1;
  }

  #pragma unroll
  for (int mf = 0; mf < 2; ++mf)
    #pragma unroll
    for (int nf = 0; nf < 4; ++nf)
      #pragma unroll
      for (int r = 0; r < 4; ++r) {
        int row = i0 + wm * 32 + mf * 16 + lq * 4 + r;
        int col = fh + wn * 64 + nf * 16 + l15;
        out[((size_t)bb * N_NODES + row) * FDIM + col] = fmaxf(acc[mf][nf][r], 0.0f);
      }
}

extern "C" void kernel_launch(void* const* d_in, const int* in_sizes, int n_in,
                              void* d_out, int out_size, void* d_ws, size_t ws_size,
                              hipStream_t stream) {
  const float* inp = (const float*)d_in[0];
  const int*   adj = (const int*)d_in[1];
  const float* W   = (const float*)d_in[2];
  const float* a   = (const float*)d_in[3];
  float* out = (float*)d_out;

  char* ws = (char*)d_ws;
  __hip_bfloat16* hT   = (__hip_bfloat16*)ws;            // 8*256*2048*2      = 8,388,608
  uint32_t* adjp       = (uint32_t*)(ws + 8388608);      // 2048*64*4         =   524,288
  float* e_src         = (float*)(ws + 8912896);         // 16384*4
  float* e_dst         = (float*)(ws + 8978432);
  float* mrow          = (float*)(ws + 9043968);
  float* ilrow         = (float*)(ws + 9109504);
  __hip_bfloat16* WT16 = (__hip_bfloat16*)(ws + 9175040);// 256*256*2         =   131,072
  float* wa1           = (float*)(ws + 9306112);         // 256*4
  float* wa2           = (float*)(ws + 9307136);         // 256*4  -> end ~9.31 MB

  k_pack<<<512, 256, 0, stream>>>(adj, adjp);
  k_prep<<<20, 256, 0, stream>>>(W, a, WT16, wa1, wa2);
  k_h<<<512, 256, 0, stream>>>(inp, WT16, wa1, wa2, hT, e_src, e_dst);
  k_ml<<<4096, 256, 0, stream>>>(adjp, e_src, e_dst, mrow, ilrow);
  k_pv<<<512, 256, 0, stream>>>(hT, adjp, e_src, e_dst, mrow, ilrow, out);
}

// Round 3
// 92.739 us; speedup vs baseline: 1.4718x; 1.3668x over previous
//
#include <hip/hip_runtime.h>
#include <hip/hip_bf16.h>
#include <stdint.h>

#define N_NODES 2048
#define FDIM 256

typedef short bf16x8 __attribute__((ext_vector_type(8)));   // 8 bf16 = 4 VGPRs (MFMA A/B frag)
typedef float f32x4 __attribute__((ext_vector_type(4)));
typedef unsigned short u16x4 __attribute__((ext_vector_type(4)));

static __device__ __forceinline__ unsigned short bf16r(float x) {
  __hip_bfloat16 h = __float2bfloat16(x);
  return __builtin_bit_cast(unsigned short, h);
}

static __device__ __forceinline__ void gl_lds16(const void* g, void* l) {
  __builtin_amdgcn_global_load_lds(
      (const __attribute__((address_space(1))) unsigned int*)g,
      (__attribute__((address_space(3))) unsigned int*)l, 16, 0, 0);
}

// ---------------- k_prep: WT16 = bf16(W^T) [f][k]; wa1 = W@a1, wa2 = W@a2 (fp32) ---------------
__global__ __launch_bounds__(256) void k_prep(const float* __restrict__ W, const float* __restrict__ a,
                                              __hip_bfloat16* __restrict__ WT16,
                                              float* __restrict__ wa1, float* __restrict__ wa2) {
  int bid = blockIdx.x, t = threadIdx.x;
  if (bid < 16) {
    __shared__ __hip_bfloat16 T[64][67];
    int k0 = (bid & 3) * 64, f0 = (bid >> 2) * 64;
    int r = t >> 2, c0 = (t & 3) * 16;
    #pragma unroll
    for (int i = 0; i < 4; ++i) {
      f32x4 v = *(const f32x4*)(W + (size_t)(k0 + r) * FDIM + f0 + c0 + i * 4);
      #pragma unroll
      for (int j = 0; j < 4; ++j) T[r][c0 + i * 4 + j] = __float2bfloat16(v[j]);
    }
    __syncthreads();
    int fr = t >> 2, kc = (t & 3) * 16;
    unsigned short buf[16];
    #pragma unroll
    for (int i = 0; i < 16; ++i) buf[i] = __builtin_bit_cast(unsigned short, T[kc + i][fr]);
    uint4* dst = (uint4*)(WT16 + (size_t)(f0 + fr) * FDIM + k0 + kc);
    dst[0] = *(uint4*)&buf[0];
    dst[1] = *(uint4*)&buf[8];
  } else {
    int k = (bid - 16) * 64 + (t >> 2), q = t & 3;
    float s1 = 0.f, s2 = 0.f;
    #pragma unroll
    for (int i = 0; i < 16; ++i) {
      int f = q * 64 + i * 4;
      f32x4 w  = *(const f32x4*)(W + (size_t)k * FDIM + f);
      f32x4 v1 = *(const f32x4*)(a + f);
      f32x4 v2 = *(const f32x4*)(a + FDIM + f);
      #pragma unroll
      for (int j = 0; j < 4; ++j) { s1 += w[j] * v1[j]; s2 += w[j] * v2[j]; }
    }
    s1 += __shfl_xor(s1, 1); s1 += __shfl_xor(s1, 2);
    s2 += __shfl_xor(s2, 1); s2 += __shfl_xor(s2, 2);
    if (q == 0) { wa1[k] = s1; wa2[k] = s2; }
  }
}

// ---------------- k_h: hT = bf16(inp@W)^T via MFMA; e_src/e_dst = inp@wa (exact fp32) ----------
__global__ __launch_bounds__(256) void k_h(const float* __restrict__ inp,
                                           const __hip_bfloat16* __restrict__ WT16,
                                           const float* __restrict__ wa1, const float* __restrict__ wa2,
                                           __hip_bfloat16* __restrict__ hT,
                                           float* __restrict__ e_src, float* __restrict__ e_dst) {
  __shared__ char lds_raw[20480];
  __hip_bfloat16* Asm = (__hip_bfloat16*)lds_raw;  // [32][264] bf16
  int t = threadIdx.x;
  int r0 = blockIdx.x * 32;
  int b = r0 >> 11, j0 = r0 & (N_NODES - 1);
  {
    int r = t >> 3, q = t & 7, c0 = q * 32;
    const float* ip = inp + (size_t)(r0 + r) * FDIM + c0;
    float s1 = 0.f, s2 = 0.f;
    #pragma unroll
    for (int i = 0; i < 8; ++i) {
      f32x4 v  = *(const f32x4*)(ip + i * 4);
      f32x4 u1 = *(const f32x4*)(wa1 + c0 + i * 4);
      f32x4 u2 = *(const f32x4*)(wa2 + c0 + i * 4);
      u16x4 pk;
      #pragma unroll
      for (int j = 0; j < 4; ++j) {
        s1 += v[j] * u1[j];
        s2 += v[j] * u2[j];
        pk[j] = bf16r(v[j]);
      }
      *(u16x4*)(Asm + r * 264 + c0 + i * 4) = pk;
    }
    s1 += __shfl_xor(s1, 1); s1 += __shfl_xor(s1, 2); s1 += __shfl_xor(s1, 4);
    s2 += __shfl_xor(s2, 1); s2 += __shfl_xor(s2, 2); s2 += __shfl_xor(s2, 4);
    if (q == 0) { e_src[r0 + r] = s1; e_dst[r0 + r] = s2; }
  }
  __syncthreads();

  int lane = t & 63, wv = t >> 6, l15 = lane & 15, lq = lane >> 4;
  int f0 = wv * 64;
  f32x4 acc[2][4];
  #pragma unroll
  for (int mf = 0; mf < 2; ++mf)
    #pragma unroll
    for (int nf = 0; nf < 4; ++nf)
      #pragma unroll
      for (int e = 0; e < 4; ++e) acc[mf][nf][e] = 0.f;

  #pragma unroll
  for (int ks = 0; ks < 8; ++ks) {
    int k0 = ks * 32;
    bf16x8 af[2], bfr[4];
    #pragma unroll
    for (int mf = 0; mf < 2; ++mf)
      af[mf] = *(const bf16x8*)(Asm + (mf * 16 + l15) * 264 + k0 + lq * 8);
    #pragma unroll
    for (int nf = 0; nf < 4; ++nf)
      bfr[nf] = *(const bf16x8*)(WT16 + (size_t)(f0 + nf * 16 + l15) * FDIM + k0 + lq * 8);
    #pragma unroll
    for (int mf = 0; mf < 2; ++mf)
      #pragma unroll
      for (int nf = 0; nf < 4; ++nf)
        acc[mf][nf] = __builtin_amdgcn_mfma_f32_16x16x32_bf16(af[mf], bfr[nf], acc[mf][nf], 0, 0, 0);
  }

  __syncthreads();
  __hip_bfloat16* Tsm = (__hip_bfloat16*)lds_raw;  // [256][40] bf16
  #pragma unroll
  for (int mf = 0; mf < 2; ++mf)
    #pragma unroll
    for (int nf = 0; nf < 4; ++nf) {
      u16x4 pk;
      #pragma unroll
      for (int r = 0; r < 4; ++r) pk[r] = bf16r(acc[mf][nf][r]);
      int fl = f0 + nf * 16 + l15;
      int jl = mf * 16 + lq * 4;
      *(u16x4*)(Tsm + fl * 40 + jl) = pk;
    }
  __syncthreads();
  {
    const uint4* src = (const uint4*)(Tsm + t * 40);
    uint4* dst = (uint4*)(hT + ((size_t)b * FDIM + t) * N_NODES + j0);
    dst[0] = src[0]; dst[1] = src[1]; dst[2] = src[2]; dst[3] = src[3];
  }
}

// ====================== BIG-WS PATH ============================================================
// ---------------- k_mlp: one block per node i; wave w = batch w; writes P[b][i][:] bf16 --------
__global__ __launch_bounds__(512) void k_mlp(const int* __restrict__ adj,
                                             const float* __restrict__ e_src,
                                             const float* __restrict__ e_dst,
                                             __hip_bfloat16* __restrict__ P) {
  int t = threadIdx.x, i = blockIdx.x;
  int b = t >> 6, l = t & 63;
  float es = e_src[(b << 11) + i];
  const float* edb = e_dst + ((size_t)b << 11);
  const int* arow = adj + (size_t)i * N_NODES;
  float ev[8][4];
  float mx = -3e38f;
  #pragma unroll
  for (int it = 0; it < 8; ++it) {
    int j0 = it * 256 + l * 4;
    int4 av  = *(const int4*)(arow + j0);
    f32x4 ed = *(const f32x4*)(edb + j0);
    const int* avp = (const int*)&av;
    #pragma unroll
    for (int c = 0; c < 4; ++c) {
      float s = es + ed[c];
      float lr = fmaxf(s, 0.01f * s);
      float e = (avp[c] != 0) ? lr : -1e9f;
      ev[it][c] = e;
      mx = fmaxf(mx, e);
    }
  }
  #pragma unroll
  for (int m = 1; m <= 32; m <<= 1) mx = fmaxf(mx, __shfl_xor(mx, m));
  float sum = 0.f;
  #pragma unroll
  for (int it = 0; it < 8; ++it)
    #pragma unroll
    for (int c = 0; c < 4; ++c) {
      ev[it][c] = __expf(ev[it][c] - mx);
      sum += ev[it][c];
    }
  #pragma unroll
  for (int m = 1; m <= 32; m <<= 1) sum += __shfl_xor(sum, m);
  float il = 1.0f / sum;
  __hip_bfloat16* Pr = P + (((size_t)b << 11) + i) * N_NODES;
  #pragma unroll
  for (int it = 0; it < 8; ++it) {
    int j0 = it * 256 + l * 4;
    u16x4 pk;
    #pragma unroll
    for (int c = 0; c < 4; ++c) pk[c] = bf16r(ev[it][c] * il);
    *(u16x4*)(Pr + j0) = pk;
  }
}

// ---------------- k_pv: out = relu(P @ H), streaming MFMA GEMM ---------------------------------
// grid 256 (b = bid&7 XCD-pinned, i-tile = bid>>3), 512 thr / 8 waves (wm=wv>>1, wn=wv&1).
// tile 64i x 256f, BK=64. A(8KB)+B(32KB) dbuf LDS via global_load_lds, T2 swizzle (rule #21).
__global__ __launch_bounds__(512) void k_pv(const __hip_bfloat16* __restrict__ P,
                                            const __hip_bfloat16* __restrict__ hT,
                                            float* __restrict__ out) {
  __shared__ __hip_bfloat16 Asm[2 * 64 * 64];    // 16 KB
  __shared__ __hip_bfloat16 Bsm[2 * 256 * 64];   // 64 KB
  int t = threadIdx.x;
  int b = blockIdx.x & 7;
  int i0 = (blockIdx.x >> 3) * 64;
  int lane = t & 63, wv = t >> 6, l15 = lane & 15, lq = lane >> 4;
  int wm = wv >> 1, wn = wv & 1;
  const __hip_bfloat16* Ab  = P  + ((size_t)(b << 11) + i0) * N_NODES;
  const __hip_bfloat16* hTb = hT + (size_t)b * FDIM * N_NODES;

  // staging: linear LDS dest, inverse-swizzled global source (chunk ^= row&7)
  int sr = t >> 3, sc = t & 7;
  auto stage = [&](int buf, int js) {
    {
      int cs = sc ^ (sr & 7);
      gl_lds16(Ab + (size_t)sr * N_NODES + js + cs * 8, Asm + buf * 4096 + wv * 512);
    }
    #pragma unroll
    for (int p = 0; p < 4; ++p) {
      int r = p * 64 + sr;
      int cs = sc ^ (r & 7);
      gl_lds16(hTb + (size_t)r * N_NODES + js + cs * 8, Bsm + buf * 16384 + p * 4096 + wv * 512);
    }
  };

  f32x4 acc[8];
  #pragma unroll
  for (int nf = 0; nf < 8; ++nf)
    #pragma unroll
    for (int e = 0; e < 4; ++e) acc[nf][e] = 0.f;

  stage(0, 0);
  __syncthreads();

  int arow = wm * 16 + l15;          // A row within tile
  for (int ks = 0; ks < 32; ++ks) {
    int cur = ks & 1;
    if (ks != 31) stage(cur ^ 1, (ks + 1) * 64);
    const __hip_bfloat16* Al = Asm + cur * 4096;
    const __hip_bfloat16* Bl = Bsm + cur * 16384;
    #pragma unroll
    for (int ko = 0; ko < 2; ++ko) {
      int g = ko * 4 + lq;
      bf16x8 af = *(const bf16x8*)(Al + arow * 64 + (g ^ (arow & 7)) * 8);
      #pragma unroll
      for (int nf = 0; nf < 8; ++nf) {
        int br = wn * 128 + nf * 16 + l15;
        bf16x8 bfr = *(const bf16x8*)(Bl + br * 64 + (g ^ (br & 7)) * 8);
        acc[nf] = __builtin_amdgcn_mfma_f32_16x16x32_bf16(af, bfr, acc[nf], 0, 0, 0);
      }
    }
    __syncthreads();
  }

  #pragma unroll
  for (int nf = 0; nf < 8; ++nf)
    #pragma unroll
    for (int r = 0; r < 4; ++r) {
      int row = i0 + wm * 16 + lq * 4 + r;
      int col = wn * 128 + nf * 16 + l15;
      out[((size_t)(b << 11) + row) * FDIM + col] = fmaxf(acc[nf][r], 0.0f);
    }
}

// ====================== FALLBACK (small ws): round-2 proven path ===============================
__global__ __launch_bounds__(256) void k_pack(const int* __restrict__ adj, uint32_t* __restrict__ adjp) {
  int t = threadIdx.x;
  int lane = t & 63;
  int i = blockIdx.x * 4 + (t >> 6);
  const int* row = adj + (size_t)i * N_NODES;
  #pragma unroll
  for (int it = 0; it < 32; ++it) {
    int v = row[it * 64 + lane];
    unsigned long long m = __ballot(v != 0);
    if (lane == 0) {
      adjp[i * 64 + it * 2]     = (uint32_t)(m & 0xffffffffull);
      adjp[i * 64 + it * 2 + 1] = (uint32_t)(m >> 32);
    }
  }
}

__global__ __launch_bounds__(256) void k_ml(const uint32_t* __restrict__ adjp,
                                            const float* __restrict__ e_src,
                                            const float* __restrict__ e_dst,
                                            float* __restrict__ mrow, float* __restrict__ ilrow) {
  int t = threadIdx.x;
  int lane = t & 63;
  int r = blockIdx.x * 4 + (t >> 6);
  int b = r >> 11, i = r & (N_NODES - 1);
  float es = e_src[r];
  const float* edb = e_dst + ((size_t)b << 11);
  const uint32_t* arow = adjp + (size_t)i * 64;
  float ev[32];
  float mx = -3e38f;
  #pragma unroll
  for (int it = 0; it < 32; ++it) {
    int j = it * 64 + lane;
    float ed = edb[j];
    uint32_t w = arow[j >> 5];
    float s = es + ed;
    float lr = fmaxf(s, 0.01f * s);
    float e = ((w >> (j & 31)) & 1u) ? lr : -1e9f;
    ev[it] = e;
    mx = fmaxf(mx, e);
  }
  #pragma unroll
  for (int m = 1; m <= 32; m <<= 1) mx = fmaxf(mx, __shfl_xor(mx, m));
  float sum = 0.f;
  #pragma unroll
  for (int it = 0; it < 32; ++it) sum += __expf(ev[it] - mx);
  #pragma unroll
  for (int m = 1; m <= 32; m <<= 1) sum += __shfl_xor(sum, m);
  if (lane == 0) { mrow[r] = mx; ilrow[r] = 1.0f / sum; }
}

__global__ __launch_bounds__(256) void k_pv_f(const __hip_bfloat16* __restrict__ hT,
                                              const uint32_t* __restrict__ adjp,
                                              const float* __restrict__ e_src,
                                              const float* __restrict__ e_dst,
                                              const float* __restrict__ mrow,
                                              const float* __restrict__ ilrow,
                                              float* __restrict__ out) {
  __shared__ __hip_bfloat16 Psm[2][64 * 40];
  int t = threadIdx.x;
  int bb = blockIdx.x & 7;
  int i0 = ((blockIdx.x >> 3) & 31) * 64;
  int fh = (blockIdx.x >> 8) * 128;
  int ip = t >> 2, jq = t & 3;
  int rflat = (bb << 11) + i0 + ip;
  float es = e_src[rflat], mi = mrow[rflat], ili = ilrow[rflat];
  const uint32_t* arow = adjp + (size_t)(i0 + ip) * 64;
  const float* edb = e_dst + ((size_t)bb << 11);
  const __hip_bfloat16* hTb = hT + (size_t)bb * FDIM * N_NODES;
  int lane = t & 63, wv = t >> 6, l15 = lane & 15, lq = lane >> 4;
  int wm = wv >> 1, wn = wv & 1;
  const __hip_bfloat16* bp[4];
  #pragma unroll
  for (int nf = 0; nf < 4; ++nf)
    bp[nf] = hTb + (size_t)(fh + wn * 64 + nf * 16 + l15) * N_NODES + lq * 8;

  auto computeP = [&](int js) -> uint4 {
    uint32_t word = arow[js >> 5] >> (jq * 8);
    f32x4 e0 = *(const f32x4*)(edb + js + jq * 8);
    f32x4 e1 = *(const f32x4*)(edb + js + jq * 8 + 4);
    unsigned short u[8];
    #pragma unroll
    for (int d = 0; d < 8; ++d) {
      float edv = (d < 4) ? e0[d] : e1[d & 3];
      float s = es + edv;
      float lr = fmaxf(s, 0.01f * s);
      float e = ((word >> d) & 1u) ? lr : -1e9f;
      u[d] = bf16r(__expf(e - mi) * ili);
    }
    uint4 r;
    r.x = (uint32_t)u[0] | ((uint32_t)u[1] << 16);
    r.y = (uint32_t)u[2] | ((uint32_t)u[3] << 16);
    r.z = (uint32_t)u[4] | ((uint32_t)u[5] << 16);
    r.w = (uint32_t)u[6] | ((uint32_t)u[7] << 16);
    return r;
  };

  f32x4 acc[2][4];
  #pragma unroll
  for (int mf = 0; mf < 2; ++mf)
    #pragma unroll
    for (int nf = 0; nf < 4; ++nf)
      #pragma unroll
      for (int e = 0; e < 4; ++e) acc[mf][nf][e] = 0.f;

  {
    uint4 p0 = computeP(0);
    *(uint4*)((char*)Psm[0] + ip * 80 + jq * 16) = p0;
  }
  bf16x8 bcur[4];
  #pragma unroll
  for (int nf = 0; nf < 4; ++nf) bcur[nf] = *(const bf16x8*)(bp[nf]);
  __syncthreads();

  int cur = 0;
  for (int js = 0; js < N_NODES; js += 32) {
    bf16x8 bn[4];
    bool more = (js + 32) < N_NODES;
    if (more) {
      #pragma unroll
      for (int nf = 0; nf < 4; ++nf) bn[nf] = *(const bf16x8*)(bp[nf] + js + 32);
      uint4 pn = computeP(js + 32);
      *(uint4*)((char*)Psm[cur ^ 1] + ip * 80 + jq * 16) = pn;
    }
    bf16x8 af[2];
    #pragma unroll
    for (int mf = 0; mf < 2; ++mf)
      af[mf] = *(const bf16x8*)((char*)Psm[cur] + (wm * 32 + mf * 16 + l15) * 80 + lq * 16);
    #pragma unroll
    for (int mf = 0; mf < 2; ++mf)
      #pragma unroll
      for (int nf = 0; nf < 4; ++nf)
        acc[mf][nf] = __builtin_amdgcn_mfma_f32_16x16x32_bf16(af[mf], bcur[nf], acc[mf][nf], 0, 0, 0);
    __syncthreads();
    if (more) {
      #pragma unroll
      for (int nf = 0; nf < 4; ++nf) bcur[nf] = bn[nf];
    }
    cur ^= 1;
  }

  #pragma unroll
  for (int mf = 0; mf < 2; ++mf)
    #pragma unroll
    for (int nf = 0; nf < 4; ++nf)
      #pragma unroll
      for (int r = 0; r < 4; ++r) {
        int row = i0 + wm * 32 + mf * 16 + lq * 4 + r;
        int col = fh + wn * 64 + nf * 16 + l15;
        out[((size_t)bb * N_NODES + row) * FDIM + col] = fmaxf(acc[mf][nf][r], 0.0f);
      }
}

extern "C" void kernel_launch(void* const* d_in, const int* in_sizes, int n_in,
                              void* d_out, int out_size, void* d_ws, size_t ws_size,
                              hipStream_t stream) {
  const float* inp = (const float*)d_in[0];
  const int*   adj = (const int*)d_in[1];
  const float* W   = (const float*)d_in[2];
  const float* a   = (const float*)d_in[3];
  float* out = (float*)d_out;
  char* ws = (char*)d_ws;

  const size_t NEED_BIG = 75761664ull;   // P 67.1MB + hT 8.4MB + e/WT/wa
  if (ws_size >= NEED_BIG) {
    __hip_bfloat16* P    = (__hip_bfloat16*)ws;               // 67,108,864
    __hip_bfloat16* hT   = (__hip_bfloat16*)(ws + 67108864);  //  8,388,608
    float* e_src         = (float*)(ws + 75497472);           //     65,536
    float* e_dst         = (float*)(ws + 75563008);           //     65,536
    __hip_bfloat16* WT16 = (__hip_bfloat16*)(ws + 75628544);  //    131,072
    float* wa1           = (float*)(ws + 75759616);           //      1,024
    float* wa2           = (float*)(ws + 75760640);           //      1,024

    k_prep<<<20, 256, 0, stream>>>(W, a, WT16, wa1, wa2);
    k_h<<<512, 256, 0, stream>>>(inp, WT16, wa1, wa2, hT, e_src, e_dst);
    k_mlp<<<2048, 512, 0, stream>>>(adj, e_src, e_dst, P);
    k_pv<<<256, 512, 0, stream>>>(P, hT, out);
  } else {
    __hip_bfloat16* hT   = (__hip_bfloat16*)ws;
    uint32_t* adjp       = (uint32_t*)(ws + 8388608);
    float* e_src         = (float*)(ws + 8912896);
    float* e_dst         = (float*)(ws + 8978432);
    float* mrow          = (float*)(ws + 9043968);
    float* ilrow         = (float*)(ws + 9109504);
    __hip_bfloat16* WT16 = (__hip_bfloat16*)(ws + 9175040);
    float* wa1           = (float*)(ws + 9306112);
    float* wa2           = (float*)(ws + 9307136);

    k_pack<<<512, 256, 0, stream>>>(adj, adjp);
    k_prep<<<20, 256, 0, stream>>>(W, a, WT16, wa1, wa2);
    k_h<<<512, 256, 0, stream>>>(inp, WT16, wa1, wa2, hT, e_src, e_dst);
    k_ml<<<4096, 256, 0, stream>>>(adjp, e_src, e_dst, mrow, ilrow);
    k_pv_f<<<512, 256, 0, stream>>>(hT, adjp, e_src, e_dst, mrow, ilrow, out);
  }
}